// Round 6
// baseline (425.051 us; speedup 1.0000x reference)
//
#include <hip/hip_runtime.h>
#include <math.h>

typedef unsigned int u32;
typedef unsigned short u16;

#define B_  2
#define S_  2048
#define D_  1024
#define H_  16
#define DK_ 64
#define FF_ 4096
#define NEG_ -1000000000.0f

typedef __attribute__((ext_vector_type(8))) short short8;
typedef __attribute__((ext_vector_type(4))) float floatx4;
typedef __attribute__((ext_vector_type(4))) unsigned short ushort4_t;

__device__ inline u16 f2b(float f) {
    union { float f; u32 u; } v; v.f = f;
    u32 r = (v.u + 0x7fffu + ((v.u >> 16) & 1u)) >> 16;
    return (u16)r;
}
__device__ inline float b2f(u16 b) {
    union { u32 u; float f; } v; v.u = ((u32)b) << 16;
    return v.f;
}

__device__ inline void gl_lds16(const u16* g, u16* l) {
    __builtin_amdgcn_global_load_lds((const __attribute__((address_space(1))) u32*)g,
                                     (__attribute__((address_space(3))) u32*)l, 16, 0, 0);
}

// ------- 4x square (1024x1024) weight transpose+convert in one launch -------
__global__ void tconv4(const float* __restrict__ W0, const float* __restrict__ W1_,
                       const float* __restrict__ W2_, const float* __restrict__ W3,
                       u16* __restrict__ dstBase) {
    __shared__ float tile[32][33];
    int z = blockIdx.z;
    const float* Wm = (z == 0) ? W0 : (z == 1) ? W1_ : (z == 2) ? W2_ : W3;
    u16* Wt = dstBase + (size_t)z * 1024 * 1024;
    const int K = 1024, N = 1024;
    int n0 = blockIdx.x * 32, k0 = blockIdx.y * 32;
    int tx = threadIdx.x & 31, ty = threadIdx.x >> 5;
#pragma unroll
    for (int r = 0; r < 32; r += 8)
        tile[ty + r][tx] = Wm[(size_t)(k0 + ty + r) * N + n0 + tx];
    __syncthreads();
#pragma unroll
    for (int r = 0; r < 32; r += 8)
        Wt[(size_t)(n0 + ty + r) * K + k0 + tx] = f2b(tile[tx][ty + r]);
}

__global__ void tconv(const float* __restrict__ Wm, u16* __restrict__ Wt, int K, int N) {
    __shared__ float tile[32][33];
    int n0 = blockIdx.x * 32, k0 = blockIdx.y * 32;
    int tx = threadIdx.x & 31, ty = threadIdx.x >> 5;
#pragma unroll
    for (int r = 0; r < 32; r += 8)
        tile[ty + r][tx] = Wm[(size_t)(k0 + ty + r) * N + n0 + tx];
    __syncthreads();
#pragma unroll
    for (int r = 0; r < 32; r += 8)
        Wt[(size_t)(n0 + ty + r) * K + k0 + tx] = f2b(tile[tx][ty + r]);
}

__global__ void catbias(const float* __restrict__ bq, const float* __restrict__ bk,
                        const float* __restrict__ bv, float* __restrict__ out) {
    int i = blockIdx.x * 256 + threadIdx.x;
    float v = (i < 1024) ? bq[i] : (i < 2048) ? bk[i - 1024] : bv[i - 2048];
    out[i] = v;
}

// ---- mask tile reduction: tflag[it][jt] = all(mask[128it..][128jt..] != 0) ----
__global__ __launch_bounds__(256)
void mask_tiles(const int* __restrict__ mask, int* __restrict__ tflag) {
    int jt = blockIdx.x, it = blockIdx.y;
    const int* base = mask + (size_t)it * 128 * S_ + jt * 128;
    int t = threadIdx.x;
    int ok = 1;
    for (int e = t; e < 128 * 32; e += 256) {
        int r = e >> 5, c4 = e & 31;
        int4 vv = *(const int4*)&base[(size_t)r * S_ + c4 * 4];
        ok &= (vv.x != 0) & (vv.y != 0) & (vv.z != 0) & (vv.w != 0);
    }
    ok = (int)__all(ok);
    __shared__ int red[4];
    if ((t & 63) == 0) red[t >> 6] = ok;
    __syncthreads();
    if (t == 0) tflag[it * 16 + jt] = red[0] & red[1] & red[2] & red[3];
}

// ---------------- LayerNorm -> bf16 out (shuffle reduce, 2 barriers) ----------------
__global__ __launch_bounds__(256)
void ln_bf16(const float* __restrict__ x, const float* __restrict__ g,
             const float* __restrict__ b, u16* __restrict__ out) {
    int row = blockIdx.x, t = threadIdx.x;
    int lane = t & 63, w = t >> 6;
    const float* xr = x + (size_t)row * D_;
    __shared__ float red[8];
    int col0 = t * 4;
    float4 xv = *(const float4*)&xr[col0];
    float v0 = xv.x, v1 = xv.y, v2 = xv.z, v3 = xv.w;
    float s = v0 + v1 + v2 + v3;
    s += __shfl_xor(s, 1); s += __shfl_xor(s, 2); s += __shfl_xor(s, 4);
    s += __shfl_xor(s, 8); s += __shfl_xor(s, 16); s += __shfl_xor(s, 32);
    if (lane == 0) red[w] = s;
    __syncthreads();
    float mu = (red[0] + red[1] + red[2] + red[3]) * (1.0f / D_);
    float d0 = v0 - mu, d1 = v1 - mu, d2 = v2 - mu, d3 = v3 - mu;
    float vs = d0 * d0 + d1 * d1 + d2 * d2 + d3 * d3;
    vs += __shfl_xor(vs, 1); vs += __shfl_xor(vs, 2); vs += __shfl_xor(vs, 4);
    vs += __shfl_xor(vs, 8); vs += __shfl_xor(vs, 16); vs += __shfl_xor(vs, 32);
    if (lane == 0) red[4 + w] = vs;
    __syncthreads();
    float rstd = rsqrtf((red[4] + red[5] + red[6] + red[7]) * (1.0f / D_) + 1e-5f);
    float4 gv = *(const float4*)&g[col0];
    float4 bv = *(const float4*)&b[col0];
    ushort4_t o;
    o[0] = f2b(d0 * rstd * gv.x + bv.x);
    o[1] = f2b(d1 * rstd * gv.y + bv.y);
    o[2] = f2b(d2 * rstd * gv.z + bv.z);
    o[3] = f2b(d3 * rstd * gv.w + bv.w);
    *(ushort4_t*)&out[(size_t)row * D_ + col0] = o;
}

// ---- fused split-K merge + residual + bias + LayerNorm (shuffle reduce) ----
__global__ __launch_bounds__(256)
void merge_ln(const u16* __restrict__ P, const float* __restrict__ x,
              const float* __restrict__ bo, const float* __restrict__ g,
              const float* __restrict__ bl, float* __restrict__ x1,
              u16* __restrict__ n2) {
    const size_t MN = (size_t)B_ * S_ * D_;
    int row = blockIdx.x, t = threadIdx.x;
    int lane = t & 63, w = t >> 6;
    size_t base = (size_t)row * D_;
    __shared__ float red[8];
    int col0 = t * 4;
    float4 xv = *(const float4*)&x[base + col0];
    float4 bv = *(const float4*)&bo[col0];
    ushort4_t p0 = *(const ushort4_t*)&P[base + col0];
    ushort4_t p1 = *(const ushort4_t*)&P[MN + base + col0];
    float v0 = xv.x + bv.x + b2f(p0[0]) + b2f(p1[0]);
    float v1 = xv.y + bv.y + b2f(p0[1]) + b2f(p1[1]);
    float v2 = xv.z + bv.z + b2f(p0[2]) + b2f(p1[2]);
    float v3 = xv.w + bv.w + b2f(p0[3]) + b2f(p1[3]);
    float s = v0 + v1 + v2 + v3;
    s += __shfl_xor(s, 1); s += __shfl_xor(s, 2); s += __shfl_xor(s, 4);
    s += __shfl_xor(s, 8); s += __shfl_xor(s, 16); s += __shfl_xor(s, 32);
    if (lane == 0) red[w] = s;
    __syncthreads();
    float mu = (red[0] + red[1] + red[2] + red[3]) * (1.0f / D_);
    float d0 = v0 - mu, d1 = v1 - mu, d2 = v2 - mu, d3 = v3 - mu;
    float vs = d0 * d0 + d1 * d1 + d2 * d2 + d3 * d3;
    vs += __shfl_xor(vs, 1); vs += __shfl_xor(vs, 2); vs += __shfl_xor(vs, 4);
    vs += __shfl_xor(vs, 8); vs += __shfl_xor(vs, 16); vs += __shfl_xor(vs, 32);
    if (lane == 0) red[4 + w] = vs;
    __syncthreads();
    float rstd = rsqrtf((red[4] + red[5] + red[6] + red[7]) * (1.0f / D_) + 1e-5f);
    float4 gv = *(const float4*)&g[col0];
    float4 blv = *(const float4*)&bl[col0];
    *(float4*)&x1[base + col0] = (float4){v0, v1, v2, v3};
    ushort4_t o;
    o[0] = f2b(d0 * rstd * gv.x + blv.x);
    o[1] = f2b(d1 * rstd * gv.y + blv.y);
    o[2] = f2b(d2 * rstd * gv.z + blv.z);
    o[3] = f2b(d3 * rstd * gv.w + blv.w);
    *(ushort4_t*)&n2[base + col0] = o;
}

// ---------------- 128x128x32 bf16 MFMA GEMM (4 blocks/CU) ---------
// SWZ 0: XCD-chunked swizzle (large N). SWZ 1: m-grouped decode — consecutive
// same-XCD blocks iterate all n-tiles of one m-tile, so the A panel is fetched
// once into that XCD's L2 and reused (skinny-N GEMMs: Wo, FFN2).
// EPI 0: bf16 QKV scatter (Q pre-scaled by 1/8); 2: bf16 GELU; 3: bf16 partial
template <int EPI, int SWZ>
__global__ __launch_bounds__(256, 4)
void gemm_bt(const u16* __restrict__ A, const u16* __restrict__ Bt,
             const float* __restrict__ bias, const float* __restrict__ R,
             void* __restrict__ Cv, int M, int N, int K, int ldA, int ldB) {
    __shared__ u16 As[2][128 * 32];
    __shared__ u16 Bs[2][128 * 32];
    int tid = threadIdx.x;
    int lane = tid & 63, w = tid >> 6;
    int wm = w >> 1, wn = w & 1;
    int nMt = gridDim.x, nNt = gridDim.y;
    int id = blockIdx.x + nMt * blockIdx.y;
    int m0, n0;
    if (SWZ == 0) {
        // XCD-chunked bijective swizzle (nwg % 8 == 0 for all launches here)
        int nwg = nMt * nNt;
        int qq = nwg >> 3;
        int sid = (id & 7) * qq + (id >> 3);
        m0 = (sid % nMt) * 128; n0 = (sid / nMt) * 128;
    } else {
        // m-grouped: XCD = id%8 sees {mt fixed, nt=0..7} consecutively
        int grp = 8 * nNt;
        int chunk = id / grp, rem = id % grp;
        int mt = chunk * 8 + (rem & 7), nt = rem >> 3;
        m0 = mt * 128; n0 = nt * 128;
    }
    size_t koff = (size_t)blockIdx.z * K;

    floatx4 acc[4][4];
#pragma unroll
    for (int a = 0; a < 4; a++)
#pragma unroll
        for (int b2 = 0; b2 < 4; b2++) acc[a][b2] = (floatx4){0.f, 0.f, 0.f, 0.f};

    int r4 = lane >> 2;
    int qg = ((lane & 3) ^ ((lane >> 3) & 3)) * 8;
    const u16* Ag0 = A + (size_t)(m0 + w * 16 + r4) * ldA + koff + qg;
    const u16* Bg0 = Bt + (size_t)(n0 + w * 16 + r4) * ldB + koff + qg;
    const int ldsOff = (w * 16) * 32;

    int c = lane & 15, g = lane >> 4;
    int sw = (g ^ ((c >> 1) & 3)) * 8;

    const int nIter = K >> 5;

    gl_lds16(Ag0, &As[0][ldsOff]);
    gl_lds16(Ag0 + (size_t)64 * ldA, &As[0][ldsOff + 64 * 32]);
    gl_lds16(Bg0, &Bs[0][ldsOff]);
    gl_lds16(Bg0 + (size_t)64 * ldB, &Bs[0][ldsOff + 64 * 32]);

    for (int it = 0; it < nIter; it++) {
        __syncthreads();
        int cur = it & 1, nxt = cur ^ 1;
        if (it + 1 < nIter) {
            int kk = (it + 1) << 5;
            gl_lds16(Ag0 + kk, &As[nxt][ldsOff]);
            gl_lds16(Ag0 + kk + (size_t)64 * ldA, &As[nxt][ldsOff + 64 * 32]);
            gl_lds16(Bg0 + kk, &Bs[nxt][ldsOff]);
            gl_lds16(Bg0 + kk + (size_t)64 * ldB, &Bs[nxt][ldsOff + 64 * 32]);
        }
        short8 fa[4], fb[4];
#pragma unroll
        for (int a = 0; a < 4; a++)
            fa[a] = *(const short8*)&As[cur][(wm * 64 + a * 16 + c) * 32 + sw];
#pragma unroll
        for (int b2 = 0; b2 < 4; b2++)
            fb[b2] = *(const short8*)&Bs[cur][(wn * 64 + b2 * 16 + c) * 32 + sw];
#pragma unroll
        for (int a = 0; a < 4; a++)
#pragma unroll
            for (int b2 = 0; b2 < 4; b2++)
                acc[a][b2] = __builtin_amdgcn_mfma_f32_16x16x32_bf16(fa[a], fb[b2], acc[a][b2], 0, 0, 0);
    }

    int mb = m0 + wm * 64, nb = n0 + wn * 64;
#pragma unroll
    for (int a = 0; a < 4; a++) {
#pragma unroll
        for (int b2 = 0; b2 < 4; b2++) {
            int mrow = mb + a * 16 + g * 4;
            int ncol = nb + b2 * 16 + c;
            float bv = (EPI == 3) ? 0.f : bias[ncol];
#pragma unroll
            for (int r = 0; r < 4; r++) {
                int m = mrow + r;
                float vvv = acc[a][b2][r] + bv;
                if (EPI == 0) {
                    int which = ncol >> 10, col = ncol & 1023;
                    if (which == 0) vvv *= 0.125f;  // fold 1/sqrt(DK) into Q
                    int bb = m >> 11, ss = m & 2047, hh = col >> 6, dk = col & 63;
                    ((u16*)Cv)[(size_t)which * ((size_t)B_ * S_ * D_) +
                               ((((size_t)bb * H_ + hh) * S_) + ss) * DK_ + dk] = f2b(vvv);
                } else if (EPI == 1) {
                    ((float*)Cv)[(size_t)m * N + ncol] = vvv + R[(size_t)m * N + ncol];
                } else if (EPI == 2) {
                    float u = 0.79788456080286536f * fmaf(0.044715f * vvv, vvv * vvv, vvv);
                    float th = 1.f - 2.f / (1.f + __expf(2.f * u));
                    ((u16*)Cv)[(size_t)m * N + ncol] = f2b(0.5f * vvv * (1.f + th));
                } else {
                    ((u16*)Cv)[(size_t)blockIdx.z * M * N + (size_t)m * N + ncol] = f2b(vvv);
                }
            }
        }
    }
}

// =============== 256x256x64 8-phase counted-vmcnt bf16 MFMA GEMM =================
// (round-4 structure, used only where grid == 256 blocks: FFN1)
#define BARR asm volatile("s_barrier" ::: "memory")

template <int EPI>
__global__ __launch_bounds__(512, 2)
void gemm8(const u16* __restrict__ A, const u16* __restrict__ Bt,
           const float* __restrict__ bias, void* __restrict__ Cv,
           int M, int N, int K, int ldA, int ldB) {
    __shared__ u16 sh2[65536];  // 128 KB
    const int tid = threadIdx.x;
    const int lane = tid & 63, w = tid >> 6;
    const int wm = w >> 2, wn = w & 3;
    const int c = lane & 15, g = lane >> 4;
    const int cbase = c * 128 + g * 16;
    const int xo = (c & 7) << 4;

    int nMt = gridDim.x;
    int nwg = gridDim.x * gridDim.y;
    int id = blockIdx.x + nMt * blockIdx.y;
    int qq = nwg >> 3;
    int sid = (id & 7) * qq + (id >> 3);
    int m0 = (sid % nMt) * 256, n0 = (sid / nMt) * 256;
    size_t koff = (size_t)blockIdx.z * K;

    const int nT = K >> 6, nI = nT >> 1;

    const int sr = tid >> 3;
    const int sk = ((tid & 7) * 8) ^ (((tid >> 3) & 7) << 3);
    const u16* gA0 = A + (size_t)(m0 + sr) * ldA + koff + sk;
    const u16* gB0 = Bt + (size_t)(n0 + sr) * ldB + koff + sk;
    const int dst0 = w * 512;  // u16; HW adds lane*16B

#define STG_A(t_, h_) do { \
    const u16* s_ = gA0 + (size_t)(h_) * 128 * ldA + (t_) * 64; \
    u16* l_ = &sh2[((((t_) & 1) * 2 + (h_)) * 8192) + dst0]; \
    gl_lds16(s_, l_); \
    gl_lds16(s_ + (size_t)64 * ldA, l_ + 4096); \
} while (0)
#define STG_B(t_, h_) do { \
    const u16* s_ = gB0 + (size_t)(h_) * 128 * ldB + (t_) * 64; \
    u16* l_ = &sh2[32768 + ((((t_) & 1) * 2 + (h_)) * 8192) + dst0]; \
    gl_lds16(s_, l_); \
    gl_lds16(s_ + (size_t)64 * ldB, l_ + 4096); \
} while (0)

    short8 fa[8], fb0[4], fb1[4];
    floatx4 acc[2][2][4][2];
#pragma unroll
    for (int i = 0; i < 2; i++)
#pragma unroll
        for (int j = 0; j < 2; j++)
#pragma unroll
            for (int a = 0; a < 4; a++)
#pragma unroll
                for (int b2 = 0; b2 < 2; b2++)
                    acc[i][j][a][b2] = (floatx4){0.f, 0.f, 0.f, 0.f};

#define DS_A(d_, qr_) do { \
    int rb_ = ((d_) * 2 + wm) * 16384; \
    _Pragma("unroll") for (int a_ = 0; a_ < 4; a_++) \
    _Pragma("unroll") for (int k_ = 0; k_ < 2; k_++) { \
        int lin_ = (qr_) * 8192 + a_ * 2048 + cbase + k_ * 64; \
        fa[a_ * 2 + k_] = *(const short8*)((const char*)sh2 + rb_ + (lin_ ^ xo)); } \
} while (0)
#define DS_B(d_, qc_, fb_) do { \
    int rb_ = 65536 + ((d_) * 2 + (wn >> 1)) * 16384; \
    _Pragma("unroll") for (int b_ = 0; b_ < 2; b_++) \
    _Pragma("unroll") for (int k_ = 0; k_ < 2; k_++) { \
        int lin_ = (wn & 1) * 8192 + (qc_) * 4096 + b_ * 2048 + cbase + k_ * 64; \
        fb_[b_ * 2 + k_] = *(const short8*)((const char*)sh2 + rb_ + (lin_ ^ xo)); } \
} while (0)
#define MFMA16(qr_, qc_, fb_) do { \
    __builtin_amdgcn_s_setprio(1); \
    _Pragma("unroll") for (int a_ = 0; a_ < 4; a_++) \
    _Pragma("unroll") for (int b_ = 0; b_ < 2; b_++) \
    _Pragma("unroll") for (int k_ = 0; k_ < 2; k_++) \
        acc[qr_][qc_][a_][b_] = __builtin_amdgcn_mfma_f32_16x16x32_bf16( \
            fa[a_ * 2 + k_], fb_[b_ * 2 + k_], acc[qr_][qc_][a_][b_], 0, 0, 0); \
    __builtin_amdgcn_s_setprio(0); \
} while (0)

    // prologue: tile0 full, tile1 A-halves; wait tile0 done (tile1.A in flight)
    STG_B(0, 0); STG_B(0, 1); STG_A(0, 0); STG_A(0, 1);
    STG_A(1, 0); STG_A(1, 1);
    asm volatile("s_waitcnt vmcnt(4)" ::: "memory");
    BARR;

    for (int it2 = 0; it2 < nI; it2++) {
        const int t1 = 2 * it2 + 1, tn0 = t1 + 1, tn1 = t1 + 2;
        // P1 (buf0, qr0,qc0)
        DS_A(0, 0); DS_B(0, 0, fb0);
        STG_B(t1, 0);
        MFMA16(0, 0, fb0); BARR;
        // P2 (qr0,qc1)
        DS_B(0, 1, fb1);
        STG_B(t1, 1);
        MFMA16(0, 1, fb1); BARR;
        // P3 (qr1,qc1)
        DS_A(0, 1);
        if (tn0 < nT) STG_B(tn0, 0);
        MFMA16(1, 1, fb1); BARR;
        // P4 (qr1,qc0)  -- checkpoint: t1 fully resident before P5
        if (tn0 < nT) {
            STG_B(tn0, 1);
            asm volatile("s_waitcnt vmcnt(4)" ::: "memory");
        } else {
            asm volatile("s_waitcnt vmcnt(0)" ::: "memory");
        }
        MFMA16(1, 0, fb0); BARR;
        // P5 (buf1, qr0,qc0)
        DS_A(1, 0); DS_B(1, 0, fb0);
        if (tn0 < nT) STG_A(tn0, 0);
        MFMA16(0, 0, fb0); BARR;
        // P6 (qr0,qc1)
        DS_B(1, 1, fb1);
        if (tn0 < nT) STG_A(tn0, 1);
        MFMA16(0, 1, fb1); BARR;
        // P7 (qr1,qc1)
        DS_A(1, 1);
        if (tn1 < nT) STG_A(tn1, 0);
        MFMA16(1, 1, fb1); BARR;
        // P8 (qr1,qc0) -- checkpoint: tn0 resident before next-iter P1
        if (tn1 < nT) STG_A(tn1, 1);
        if (it2 + 1 < nI) asm volatile("s_waitcnt vmcnt(4)" ::: "memory");
        MFMA16(1, 0, fb0); BARR;
    }

    // epilogue
#pragma unroll
    for (int qr = 0; qr < 2; qr++)
#pragma unroll
        for (int qc = 0; qc < 2; qc++)
#pragma unroll
            for (int a = 0; a < 4; a++)
#pragma unroll
                for (int b2 = 0; b2 < 2; b2++) {
                    int mrow = m0 + wm * 128 + qr * 64 + a * 16 + g * 4;
                    int ncol = n0 + wn * 64 + qc * 32 + b2 * 16 + c;
                    float bv = (EPI == 3) ? 0.f : bias[ncol];
#pragma unroll
                    for (int r = 0; r < 4; r++) {
                        int m = mrow + r;
                        float vvv = acc[qr][qc][a][b2][r] + bv;
                        if (EPI == 0) {
                            int which = ncol >> 10, col = ncol & 1023;
                            if (which == 0) vvv *= 0.125f;
                            int bb = m >> 11, ss = m & 2047, hh = col >> 6, dk = col & 63;
                            ((u16*)Cv)[(size_t)which * ((size_t)B_ * S_ * D_) +
                                       ((((size_t)bb * H_ + hh) * S_) + ss) * DK_ + dk] = f2b(vvv);
                        } else if (EPI == 2) {
                            float u = 0.79788456080286536f * fmaf(0.044715f * vvv, vvv * vvv, vvv);
                            float th = 1.f - 2.f / (1.f + __expf(2.f * u));
                            ((u16*)Cv)[(size_t)m * N + ncol] = f2b(0.5f * vvv * (1.f + th));
                        } else {
                            ((u16*)Cv)[(size_t)blockIdx.z * M * N + (size_t)m * N + ncol] = f2b(vvv);
                        }
                    }
                }
#undef STG_A
#undef STG_B
#undef DS_A
#undef DS_B
#undef MFMA16
}

// ---------------- FFN2 split-K merge: out = x1 + bf2 + sum_z P[z] ----------------
template <int NP>
__global__ __launch_bounds__(256)
void ffn2_merge(const u16* __restrict__ P, const float* __restrict__ x1,
                const float* __restrict__ bf2, float* __restrict__ out) {
    const size_t MN = (size_t)B_ * S_ * D_;
    int e = (blockIdx.x * 256 + threadIdx.x) * 4;
    float4 xv = *(const float4*)&x1[e];
    float4 bv = *(const float4*)&bf2[e & 1023];
    float o0 = xv.x + bv.x, o1 = xv.y + bv.y, o2 = xv.z + bv.z, o3 = xv.w + bv.w;
#pragma unroll
    for (int z = 0; z < NP; z++) {
        ushort4_t pv = *(const ushort4_t*)&P[z * MN + e];
        o0 += b2f(pv[0]); o1 += b2f(pv[1]); o2 += b2f(pv[2]); o3 += b2f(pv[3]);
    }
    *(float4*)&out[e] = (float4){o0, o1, o2, o3};
}

// ---------------- MFMA sparse strided attention, 38 KB LDS union -----------------
#define MAXB_ 14
__global__ __launch_bounds__(256)
void attn4(const u16* __restrict__ q, const u16* __restrict__ k,
           const u16* __restrict__ v, const int* __restrict__ mask,
           const int* __restrict__ tileOK, u16* __restrict__ ob) {
    __shared__ u16 sh[19456];            // 38,912 B
    u16* Kw = sh;                        // [192*72]; P[64*200] overlays later
    u16* Qs = sh + 13824;                // [64*72]
    u16* Vh = sh + 12800;                // [64*104] V^T half (built after scores)

    const int bh = blockIdx.x;
    const int i0 = (31 - blockIdx.y) * 64;
    const int b  = bh >> 4, h = bh & 15;
    const int t  = threadIdx.x;
    const int lane = t & 63, w = t >> 6;
    const int c = lane & 15, g = lane >> 4;
    const int g4 = g * 4;
    const int qloc16 = w * 16;

    const u16* qg = q + ((size_t)bh * S_ + i0) * DK_;
    const u16* kg = k + (size_t)bh * S_ * DK_;
    const u16* vg = v + (size_t)bh * S_ * DK_;

    const int wlo = (i0 >= 128) ? i0 - 128 : 0;
    const int wn  = i0 + 64 - wlo;             // 64 / 128 / 192
    const int nb  = (i0 >= 256) ? (i0 >> 7) - 1 : 0;
    const int jb0 = i0 & 127;
    const int dd0 = i0 - wlo;

    bool allOK = true;
    {
        const int* rowf = tileOK + (i0 >> 7) * 16;
        int jt0 = wlo >> 7, jt1 = (i0 + 63) >> 7;
        for (int jt = jt0; jt <= jt1; jt++) allOK &= (rowf[jt] != 0);
        for (int m = 0; m < nb; m++) allOK &= (rowf[m] != 0);
    }

    // ---- P0: stage Qs + Kw
    for (int e = t; e < 64 * 8; e += 256) {
        int row = e >> 3, dc = e & 7;
        *(short8*)&Qs[row * 72 + dc * 8] = *(const short8*)(qg + row * 64 + dc * 8);
    }
    for (int e = t; e < wn * 8; e += 256) {
        int row = e >> 3, dc = e & 7;
        *(short8*)&Kw[row * 72 + dc * 8] = *(const short8*)(kg + (size_t)(wlo + row) * 64 + dc * 8);
    }
    __syncthreads();

    // ---- P1: band scores -> sbr[m]
    float sbr[MAXB_];
    {
        short8 qv0 = *(const short8*)&Qs[(qloc16 + c) * 72 + g * 8];
        short8 qv1 = *(const short8*)&Qs[(qloc16 + c) * 72 + 32 + g * 8];
#pragma unroll
        for (int m = 0; m < MAXB_; m++) {
            sbr[m] = NEG_;
            if (m < nb) {
                int jrow = jb0 + (m << 7) + qloc16 + c;
                short8 kv0 = *(const short8*)(kg + (size_t)jrow * 64 + g * 8);
                short8 kv1 = *(const short8*)(kg + (size_t)jrow * 64 + 32 + g * 8);
                float p = 0.f;
#pragma unroll
                for (int i = 0; i < 8; i++) {
                    p += b2f((u16)qv0[i]) * b2f((u16)kv0[i]);
                    p += b2f((u16)qv1[i]) * b2f((u16)kv1[i]);
                }
                p += __shfl_xor(p, 16);
                p += __shfl_xor(p, 32);
                if (!allOK && mask[(size_t)(i0 + qloc16 + c) * S_ + jrow] == 0) p = NEG_;
                sbr[m] = p;
            }
        }
    }

    // ---- P2: window scores via MFMA
    floatx4 sc[12];
#pragma unroll
    for (int ct = 0; ct < 12; ct++) sc[ct] = (floatx4){0.f, 0.f, 0.f, 0.f};
    {
        short8 fa0 = *(const short8*)&Qs[(qloc16 + c) * 72 + g * 8];
        short8 fa1 = *(const short8*)&Qs[(qloc16 + c) * 72 + 32 + g * 8];
#pragma unroll
        for (int ct = 0; ct < 12; ct++) {
            short8 fb0 = *(const short8*)&Kw[(ct * 16 + c) * 72 + g * 8];
            short8 fb1 = *(const short8*)&Kw[(ct * 16 + c) * 72 + 32 + g * 8];
            sc[ct] = __builtin_amdgcn_mfma_f32_16x16x32_bf16(fa0, fb0, sc[ct], 0, 0, 0);
            sc[ct] = __builtin_amdgcn_mfma_f32_16x16x32_bf16(fa1, fb1, sc[ct], 0, 0, 0);
        }
    }

    // ---- P3: causal/range mask (+fallback user mask) + softmax stats
#pragma unroll
    for (int ct = 0; ct < 12; ct++) {
        int cidx = ct * 16 + c;
        int j = wlo + cidx;
#pragma unroll
        for (int r = 0; r < 4; r++) {
            int qloc = qloc16 + g4 + r;
            int d = dd0 + qloc - cidx;
            bool ok = (d >= 0) && (d <= 128);
            if (ok && !allOK) ok = (mask[(size_t)(i0 + qloc) * S_ + j] != 0);
            sc[ct][r] = ok ? sc[ct][r] : NEG_;
        }
    }

    float mv[4], inv[4];
#pragma unroll
    for (int r = 0; r < 4; r++) {
        float bs[MAXB_];
#pragma unroll
        for (int m = 0; m < MAXB_; m++)
            bs[m] = (m < nb) ? __shfl(sbr[m], g4 + r, 64) : NEG_;
        float mm = -1e30f;
#pragma unroll
        for (int ct = 0; ct < 12; ct++) mm = fmaxf(mm, sc[ct][r]);
        mm = fmaxf(mm, __shfl_xor(mm, 1));
        mm = fmaxf(mm, __shfl_xor(mm, 2));
        mm = fmaxf(mm, __shfl_xor(mm, 4));
        mm = fmaxf(mm, __shfl_xor(mm, 8));
#pragma unroll
        for (int m = 0; m < MAXB_; m++)
            if (m < nb) mm = fmaxf(mm, bs[m]);
        float sum = 0.f;
#pragma unroll
        for (int ct = 0; ct < 12; ct++) {
            float e = __expf(sc[ct][r] - mm);
            sc[ct][r] = e;
            sum += e;
        }
        sum += __shfl_xor(sum, 1);
        sum += __shfl_xor(sum, 2);
        sum += __shfl_xor(sum, 4);
        sum += __shfl_xor(sum, 8);
#pragma unroll
        for (int m = 0; m < MAXB_; m++)
            if (m < nb) sum += __expf(bs[m] - mm);
        mv[r] = mm;
        inv[r] = 1.f / sum;
    }

    // ---- P4: write P over Kw; build Vh half0 (j 0..95)
    __syncthreads();
    u16* P = Kw;
#pragma unroll
    for (int ct = 0; ct < 12; ct++)
#pragma unroll
        for (int r = 0; r < 4; r++)
            P[(qloc16 + g4 + r) * 200 + ct * 16 + c] = f2b(sc[ct][r]);

    for (int e = t; e < 768; e += 256) {
        int dc = e / 96, jl = e - dc * 96;
        short8 val = {0, 0, 0, 0, 0, 0, 0, 0};
        if (jl < wn) val = *(const short8*)(vg + (size_t)(wlo + jl) * 64 + dc * 8);
#pragma unroll
        for (int i = 0; i < 8; i++) Vh[(dc * 8 + i) * 104 + jl] = (u16)val[i];
    }
    __syncthreads();

    // ---- P5a: window PV half0 via MFMA
    floatx4 o[4];
#pragma unroll
    for (int nt = 0; nt < 4; nt++) o[nt] = (floatx4){0.f, 0.f, 0.f, 0.f};
#pragma unroll
    for (int ks = 0; ks < 3; ks++) {
        short8 pa = *(const short8*)&P[(qloc16 + c) * 200 + ks * 32 + g * 8];
#pragma unroll
        for (int nt = 0; nt < 4; nt++) {
            short8 vb = *(const short8*)&Vh[(nt * 16 + c) * 104 + ks * 32 + g * 8];
            o[nt] = __builtin_amdgcn_mfma_f32_16x16x32_bf16(pa, vb, o[nt], 0, 0, 0);
        }
    }

    // ---- P5b: rebuild Vh for half1 (j 96..191) and finish PV (uniform branch)
    if (wn > 96) {
        __syncthreads();
        for (int e = t; e < 768; e += 256) {
            int dc = e / 96, jl = e - dc * 96;
            int j2 = 96 + jl;
            short8 val = {0, 0, 0, 0, 0, 0, 0, 0};
            if (j2 < wn) val = *(const short8*)(vg + (size_t)(wlo + j2) * 64 + dc * 8);
#pragma unroll
            for (int i = 0; i < 8; i++) Vh[(dc * 8 + i) * 104 + jl] = (u16)val[i];
        }
        __syncthreads();
#pragma unroll
        for (int ks = 0; ks < 3; ks++) {
            short8 pa = *(const short8*)&P[(qloc16 + c) * 200 + 96 + ks * 32 + g * 8];
#pragma unroll
            for (int nt = 0; nt < 4; nt++) {
                short8 vb = *(const short8*)&Vh[(nt * 16 + c) * 104 + ks * 32 + g * 8];
                o[nt] = __builtin_amdgcn_mfma_f32_16x16x32_bf16(pa, vb, o[nt], 0, 0, 0);
            }
        }
    }

    // ---- P6: band PV via per-lane register loads
#pragma unroll
    for (int m = 0; m < MAXB_; m++) {
        if (m < nb) {
            int vbase = jb0 + (m << 7) + qloc16 + g4;
            u16 vv[4][4];
#pragma unroll
            for (int r = 0; r < 4; r++)
#pragma unroll
                for (int nt = 0; nt < 4; nt++)
                    vv[r][nt] = vg[(size_t)(vbase + r) * 64 + nt * 16 + c];
#pragma unroll
            for (int r = 0; r < 4; r++) {
                float bs = __shfl(sbr[m], g4 + r, 64);
                float pb = __expf(bs - mv[r]);
#pragma unroll
                for (int nt = 0; nt < 4; nt++)
                    o[nt][r] += pb * b2f(vv[r][nt]);
            }
        }
    }

    // ---- P7: normalize + write [B,S,D] bf16
#pragma unroll
    for (int nt = 0; nt < 4; nt++) {
#pragma unroll
        for (int r = 0; r < 4; r++) {
            int qi = i0 + qloc16 + g4 + r;
            ob[((size_t)b * S_ + qi) * D_ + h * 64 + nt * 16 + c] = f2b(o[nt][r] * inv[r]);
        }
    }
}

extern "C" void kernel_launch(void* const* d_in, const int* in_sizes, int n_in,
                              void* d_out, int out_size, void* d_ws, size_t ws_size,
                              hipStream_t stream) {
    const float* x    = (const float*)d_in[0];
    const int*   mask = (const int*)  d_in[1];
    const float* Wq   = (const float*)d_in[2];
    const float* bq   = (const float*)d_in[3];
    const float* Wk   = (const float*)d_in[4];
    const float* bk   = (const float*)d_in[5];
    const float* Wv   = (const float*)d_in[6];
    const float* bv   = (const float*)d_in[7];
    const float* Wo   = (const float*)d_in[8];
    const float* bo   = (const float*)d_in[9];
    const float* W1   = (const float*)d_in[10];
    const float* bf1  = (const float*)d_in[11];
    const float* W2   = (const float*)d_in[12];
    const float* bf2  = (const float*)d_in[13];
    const float* g1   = (const float*)d_in[14];
    const float* bl1  = (const float*)d_in[15];
    const float* g2   = (const float*)d_in[16];
    const float* bl2  = (const float*)d_in[17];

    char* wsb = (char*)d_ws;
    const size_t MB = 1024 * 1024;
    u16*   WtQKV  = (u16*)(wsb + 0);          // 6 MB; WtO contiguous after
    u16*   WtO    = (u16*)(wsb + 6 * MB);     // 2 MB
    u16*   Wt1    = (u16*)(wsb + 8 * MB);     // 8 MB
    u16*   Wt2    = (u16*)(wsb + 16 * MB);    // 8 MB
    u16*   n1b    = (u16*)(wsb + 24 * MB);    // 8 MB (reused as n2b)
    u16*   qkv    = (u16*)(wsb + 32 * MB);    // 24 MB (dead after attn)
    u16*   obb    = (u16*)(wsb + 56 * MB);    // 8 MB (dead after Wo gemm)
    float* x1     = (float*)(wsb + 32 * MB);  // 16 MB over dead q|k (live thru merge)
    u16*   ff1b   = (u16*)(wsb + 48 * MB);    // 33.5 MB over dead v|obb
    u16*   Ppart  = (u16*)(wsb + 82 * MB);    // 32 MB: FFN2 4x bf16 partials
    u16*   PpartO = (u16*)(wsb + 82 * MB);    // 16 MB: Wo 2x partials (dead before FFN2)
    float* bcat   = (float*)(wsb + 114 * MB); // 12 KB
    int*   tflag  = (int*)(wsb + 115 * MB);   // 1 KB
    u16*   n2b    = n1b;

    const int M = B_ * S_;  // 4096
    const size_t SZ = (size_t)B_ * S_ * D_;

    // 0. mask tile flags, weight transpose + convert, bias concat
    mask_tiles<<<dim3(16, 16), 256, 0, stream>>>(mask, tflag);
    tconv4<<<dim3(32, 32, 4), 256, 0, stream>>>(Wq, Wk, Wv, Wo, WtQKV);
    tconv<<<dim3(128, 32), 256, 0, stream>>>(W1, Wt1, 1024, 4096);
    tconv<<<dim3(32, 128), 256, 0, stream>>>(W2, Wt2, 4096, 1024);
    catbias<<<12, 256, 0, stream>>>(bq, bk, bv, bcat);

    // 1. LN1 -> bf16
    ln_bf16<<<M, 256, 0, stream>>>(x, g1, bl1, n1b);

    // 2. fused QKV projection (N=3072) -> bf16 [B,H,S,DK] x3 (Q pre-scaled 1/8)
    //    128^2 tile -> 768 blocks (3/CU): cross-block overlap fills the machine.
    gemm_bt<0, 0><<<dim3(32, 24), 256, 0, stream>>>(n1b, WtQKV, bcat, nullptr, qkv,
                                                    M, 3072, 1024, 1024, 1024);

    // 3. sparse strided attention (MFMA) -> bf16 [B,S,D]
    attn4<<<dim3(32, 32), 256, 0, stream>>>(qkv, qkv + SZ, qkv + 2 * SZ, mask, tflag, obb);

    // 4. Wo split-K=2 partials (512 blocks, 2/CU, m-grouped L2 reuse), then merge+LN2
    gemm_bt<3, 1><<<dim3(32, 8, 2), 256, 0, stream>>>(obb, WtO, nullptr, nullptr, PpartO,
                                                      M, 1024, 512, 1024, 1024);
    merge_ln<<<M, 256, 0, stream>>>(PpartO, x, bo, g2, bl2, x1, n2b);

    // 6. ff1 = GELU(n2 @ W1 + bf1) -> bf16  (256 blocks == 256 CUs: gemm8)
    gemm8<2><<<dim3(16, 16, 1), 512, 0, stream>>>(n2b, Wt1, bf1, ff1b,
                                                  M, 4096, 1024, 1024, 1024);

    // 7. FFN2 split-K=4 (1024 blocks = 4/CU, m-grouped L2 reuse): partials -> merge
    gemm_bt<3, 1><<<dim3(32, 8, 4), 256, 0, stream>>>(ff1b, Wt2, nullptr, nullptr, Ppart,
                                                      M, 1024, 1024, 4096, 4096);
    ffn2_merge<4><<<(int)(SZ / 1024), 256, 0, stream>>>(Ppart, x1, bf2, (float*)d_out);
}

// Round 7
// 361.643 us; speedup vs baseline: 1.1753x; 1.1753x over previous
//
#include <hip/hip_runtime.h>
#include <math.h>

typedef unsigned int u32;
typedef unsigned short u16;

#define B_  2
#define S_  2048
#define D_  1024
#define H_  16
#define DK_ 64
#define FF_ 4096
#define NEG_ -1000000000.0f

typedef __attribute__((ext_vector_type(8))) short short8;
typedef __attribute__((ext_vector_type(4))) float floatx4;
typedef __attribute__((ext_vector_type(4))) unsigned short ushort4_t;

__device__ inline u16 f2b(float f) {
    union { float f; u32 u; } v; v.f = f;
    u32 r = (v.u + 0x7fffu + ((v.u >> 16) & 1u)) >> 16;
    return (u16)r;
}
__device__ inline float b2f(u16 b) {
    union { u32 u; float f; } v; v.u = ((u32)b) << 16;
    return v.f;
}

__device__ inline void gl_lds16(const u16* g, u16* l) {
    __builtin_amdgcn_global_load_lds((const __attribute__((address_space(1))) u32*)g,
                                     (__attribute__((address_space(3))) u32*)l, 16, 0, 0);
}

// ------- 4x square (1024x1024) weight transpose+convert in one launch -------
__global__ void tconv4(const float* __restrict__ W0, const float* __restrict__ W1_,
                       const float* __restrict__ W2_, const float* __restrict__ W3,
                       u16* __restrict__ dstBase) {
    __shared__ float tile[32][33];
    int z = blockIdx.z;
    const float* Wm = (z == 0) ? W0 : (z == 1) ? W1_ : (z == 2) ? W2_ : W3;
    u16* Wt = dstBase + (size_t)z * 1024 * 1024;
    const int K = 1024, N = 1024;
    int n0 = blockIdx.x * 32, k0 = blockIdx.y * 32;
    int tx = threadIdx.x & 31, ty = threadIdx.x >> 5;
#pragma unroll
    for (int r = 0; r < 32; r += 8)
        tile[ty + r][tx] = Wm[(size_t)(k0 + ty + r) * N + n0 + tx];
    __syncthreads();
#pragma unroll
    for (int r = 0; r < 32; r += 8)
        Wt[(size_t)(n0 + ty + r) * K + k0 + tx] = f2b(tile[tx][ty + r]);
}

__global__ void tconv(const float* __restrict__ Wm, u16* __restrict__ Wt, int K, int N) {
    __shared__ float tile[32][33];
    int n0 = blockIdx.x * 32, k0 = blockIdx.y * 32;
    int tx = threadIdx.x & 31, ty = threadIdx.x >> 5;
#pragma unroll
    for (int r = 0; r < 32; r += 8)
        tile[ty + r][tx] = Wm[(size_t)(k0 + ty + r) * N + n0 + tx];
    __syncthreads();
#pragma unroll
    for (int r = 0; r < 32; r += 8)
        Wt[(size_t)(n0 + ty + r) * K + k0 + tx] = f2b(tile[tx][ty + r]);
}

__global__ void catbias(const float* __restrict__ bq, const float* __restrict__ bk,
                        const float* __restrict__ bv, float* __restrict__ out) {
    int i = blockIdx.x * 256 + threadIdx.x;
    float v = (i < 1024) ? bq[i] : (i < 2048) ? bk[i - 1024] : bv[i - 2048];
    out[i] = v;
}

// ---- mask tile reduction: tflag[it][jt] = all(mask[128it..][128jt..] != 0) ----
__global__ __launch_bounds__(256)
void mask_tiles(const int* __restrict__ mask, int* __restrict__ tflag) {
    int jt = blockIdx.x, it = blockIdx.y;
    const int* base = mask + (size_t)it * 128 * S_ + jt * 128;
    int t = threadIdx.x;
    int ok = 1;
    for (int e = t; e < 128 * 32; e += 256) {
        int r = e >> 5, c4 = e & 31;
        int4 vv = *(const int4*)&base[(size_t)r * S_ + c4 * 4];
        ok &= (vv.x != 0) & (vv.y != 0) & (vv.z != 0) & (vv.w != 0);
    }
    ok = (int)__all(ok);
    __shared__ int red[4];
    if ((t & 63) == 0) red[t >> 6] = ok;
    __syncthreads();
    if (t == 0) tflag[it * 16 + jt] = red[0] & red[1] & red[2] & red[3];
}

// ---------------- LayerNorm -> bf16 out (shuffle reduce, 2 barriers) ----------------
__global__ __launch_bounds__(256)
void ln_bf16(const float* __restrict__ x, const float* __restrict__ g,
             const float* __restrict__ b, u16* __restrict__ out) {
    int row = blockIdx.x, t = threadIdx.x;
    int lane = t & 63, w = t >> 6;
    const float* xr = x + (size_t)row * D_;
    __shared__ float red[8];
    int col0 = t * 4;
    float4 xv = *(const float4*)&xr[col0];
    float v0 = xv.x, v1 = xv.y, v2 = xv.z, v3 = xv.w;
    float s = v0 + v1 + v2 + v3;
    s += __shfl_xor(s, 1); s += __shfl_xor(s, 2); s += __shfl_xor(s, 4);
    s += __shfl_xor(s, 8); s += __shfl_xor(s, 16); s += __shfl_xor(s, 32);
    if (lane == 0) red[w] = s;
    __syncthreads();
    float mu = (red[0] + red[1] + red[2] + red[3]) * (1.0f / D_);
    float d0 = v0 - mu, d1 = v1 - mu, d2 = v2 - mu, d3 = v3 - mu;
    float vs = d0 * d0 + d1 * d1 + d2 * d2 + d3 * d3;
    vs += __shfl_xor(vs, 1); vs += __shfl_xor(vs, 2); vs += __shfl_xor(vs, 4);
    vs += __shfl_xor(vs, 8); vs += __shfl_xor(vs, 16); vs += __shfl_xor(vs, 32);
    if (lane == 0) red[4 + w] = vs;
    __syncthreads();
    float rstd = rsqrtf((red[4] + red[5] + red[6] + red[7]) * (1.0f / D_) + 1e-5f);
    float4 gv = *(const float4*)&g[col0];
    float4 bv = *(const float4*)&b[col0];
    ushort4_t o;
    o[0] = f2b(d0 * rstd * gv.x + bv.x);
    o[1] = f2b(d1 * rstd * gv.y + bv.y);
    o[2] = f2b(d2 * rstd * gv.z + bv.z);
    o[3] = f2b(d3 * rstd * gv.w + bv.w);
    *(ushort4_t*)&out[(size_t)row * D_ + col0] = o;
}

// ---- fused split-K merge + residual + bias + LayerNorm (shuffle reduce) ----
__global__ __launch_bounds__(256)
void merge_ln(const u16* __restrict__ P, const float* __restrict__ x,
              const float* __restrict__ bo, const float* __restrict__ g,
              const float* __restrict__ bl, float* __restrict__ x1,
              u16* __restrict__ n2) {
    const size_t MN = (size_t)B_ * S_ * D_;
    int row = blockIdx.x, t = threadIdx.x;
    int lane = t & 63, w = t >> 6;
    size_t base = (size_t)row * D_;
    __shared__ float red[8];
    int col0 = t * 4;
    float4 xv = *(const float4*)&x[base + col0];
    float4 bv = *(const float4*)&bo[col0];
    ushort4_t p0 = *(const ushort4_t*)&P[base + col0];
    ushort4_t p1 = *(const ushort4_t*)&P[MN + base + col0];
    float v0 = xv.x + bv.x + b2f(p0[0]) + b2f(p1[0]);
    float v1 = xv.y + bv.y + b2f(p0[1]) + b2f(p1[1]);
    float v2 = xv.z + bv.z + b2f(p0[2]) + b2f(p1[2]);
    float v3 = xv.w + bv.w + b2f(p0[3]) + b2f(p1[3]);
    float s = v0 + v1 + v2 + v3;
    s += __shfl_xor(s, 1); s += __shfl_xor(s, 2); s += __shfl_xor(s, 4);
    s += __shfl_xor(s, 8); s += __shfl_xor(s, 16); s += __shfl_xor(s, 32);
    if (lane == 0) red[w] = s;
    __syncthreads();
    float mu = (red[0] + red[1] + red[2] + red[3]) * (1.0f / D_);
    float d0 = v0 - mu, d1 = v1 - mu, d2 = v2 - mu, d3 = v3 - mu;
    float vs = d0 * d0 + d1 * d1 + d2 * d2 + d3 * d3;
    vs += __shfl_xor(vs, 1); vs += __shfl_xor(vs, 2); vs += __shfl_xor(vs, 4);
    vs += __shfl_xor(vs, 8); vs += __shfl_xor(vs, 16); vs += __shfl_xor(vs, 32);
    if (lane == 0) red[4 + w] = vs;
    __syncthreads();
    float rstd = rsqrtf((red[4] + red[5] + red[6] + red[7]) * (1.0f / D_) + 1e-5f);
    float4 gv = *(const float4*)&g[col0];
    float4 blv = *(const float4*)&bl[col0];
    *(float4*)&x1[base + col0] = (float4){v0, v1, v2, v3};
    ushort4_t o;
    o[0] = f2b(d0 * rstd * gv.x + blv.x);
    o[1] = f2b(d1 * rstd * gv.y + blv.y);
    o[2] = f2b(d2 * rstd * gv.z + blv.z);
    o[3] = f2b(d3 * rstd * gv.w + blv.w);
    *(ushort4_t*)&n2[base + col0] = o;
}

// ---------------- 128x128x32 bf16 MFMA GEMM (4 blocks/CU), XCD swizzle ---------
// EPI 0: bf16 QKV scatter (Q pre-scaled by 1/8); 2: bf16 GELU; 3: bf16 partial
template <int EPI>
__global__ __launch_bounds__(256, 4)
void gemm_bt(const u16* __restrict__ A, const u16* __restrict__ Bt,
             const float* __restrict__ bias, const float* __restrict__ R,
             void* __restrict__ Cv, int M, int N, int K, int ldA, int ldB) {
    __shared__ u16 As[2][128 * 32];
    __shared__ u16 Bs[2][128 * 32];
    int tid = threadIdx.x;
    int lane = tid & 63, w = tid >> 6;
    int wm = w >> 1, wn = w & 1;
    // XCD-chunked bijective swizzle (nwg % 8 == 0 for all launches here)
    int nMt = gridDim.x, nwg = gridDim.x * gridDim.y;
    int id = blockIdx.x + nMt * blockIdx.y;
    int qq = nwg >> 3;
    int sid = (id & 7) * qq + (id >> 3);
    int m0 = (sid % nMt) * 128, n0 = (sid / nMt) * 128;
    size_t koff = (size_t)blockIdx.z * K;

    floatx4 acc[4][4];
#pragma unroll
    for (int a = 0; a < 4; a++)
#pragma unroll
        for (int b2 = 0; b2 < 4; b2++) acc[a][b2] = (floatx4){0.f, 0.f, 0.f, 0.f};

    int r4 = lane >> 2;
    int qg = ((lane & 3) ^ ((lane >> 3) & 3)) * 8;
    const u16* Ag0 = A + (size_t)(m0 + w * 16 + r4) * ldA + koff + qg;
    const u16* Bg0 = Bt + (size_t)(n0 + w * 16 + r4) * ldB + koff + qg;
    const int ldsOff = (w * 16) * 32;

    int c = lane & 15, g = lane >> 4;
    int sw = (g ^ ((c >> 1) & 3)) * 8;

    const int nIter = K >> 5;

    gl_lds16(Ag0, &As[0][ldsOff]);
    gl_lds16(Ag0 + (size_t)64 * ldA, &As[0][ldsOff + 64 * 32]);
    gl_lds16(Bg0, &Bs[0][ldsOff]);
    gl_lds16(Bg0 + (size_t)64 * ldB, &Bs[0][ldsOff + 64 * 32]);

    for (int it = 0; it < nIter; it++) {
        __syncthreads();
        int cur = it & 1, nxt = cur ^ 1;
        if (it + 1 < nIter) {
            int kk = (it + 1) << 5;
            gl_lds16(Ag0 + kk, &As[nxt][ldsOff]);
            gl_lds16(Ag0 + kk + (size_t)64 * ldA, &As[nxt][ldsOff + 64 * 32]);
            gl_lds16(Bg0 + kk, &Bs[nxt][ldsOff]);
            gl_lds16(Bg0 + kk + (size_t)64 * ldB, &Bs[nxt][ldsOff + 64 * 32]);
        }
        short8 fa[4], fb[4];
#pragma unroll
        for (int a = 0; a < 4; a++)
            fa[a] = *(const short8*)&As[cur][(wm * 64 + a * 16 + c) * 32 + sw];
#pragma unroll
        for (int b2 = 0; b2 < 4; b2++)
            fb[b2] = *(const short8*)&Bs[cur][(wn * 64 + b2 * 16 + c) * 32 + sw];
#pragma unroll
        for (int a = 0; a < 4; a++)
#pragma unroll
            for (int b2 = 0; b2 < 4; b2++)
                acc[a][b2] = __builtin_amdgcn_mfma_f32_16x16x32_bf16(fa[a], fb[b2], acc[a][b2], 0, 0, 0);
    }

    int mb = m0 + wm * 64, nb = n0 + wn * 64;
#pragma unroll
    for (int a = 0; a < 4; a++) {
#pragma unroll
        for (int b2 = 0; b2 < 4; b2++) {
            int mrow = mb + a * 16 + g * 4;
            int ncol = nb + b2 * 16 + c;
            float bv = (EPI == 3) ? 0.f : bias[ncol];
#pragma unroll
            for (int r = 0; r < 4; r++) {
                int m = mrow + r;
                float vvv = acc[a][b2][r] + bv;
                if (EPI == 0) {
                    int which = ncol >> 10, col = ncol & 1023;
                    if (which == 0) vvv *= 0.125f;  // fold 1/sqrt(DK) into Q
                    int bb = m >> 11, ss = m & 2047, hh = col >> 6, dk = col & 63;
                    ((u16*)Cv)[(size_t)which * ((size_t)B_ * S_ * D_) +
                               ((((size_t)bb * H_ + hh) * S_) + ss) * DK_ + dk] = f2b(vvv);
                } else if (EPI == 1) {
                    ((float*)Cv)[(size_t)m * N + ncol] = vvv + R[(size_t)m * N + ncol];
                } else if (EPI == 2) {
                    float u = 0.79788456080286536f * fmaf(0.044715f * vvv, vvv * vvv, vvv);
                    float th = 1.f - 2.f / (1.f + __expf(2.f * u));
                    ((u16*)Cv)[(size_t)m * N + ncol] = f2b(0.5f * vvv * (1.f + th));
                } else {
                    ((u16*)Cv)[(size_t)blockIdx.z * M * N + (size_t)m * N + ncol] = f2b(vvv);
                }
            }
        }
    }
}

// =============== 256x256x64 8-phase counted-vmcnt bf16 MFMA GEMM =================
// Used only where grid == 256 blocks (full fill at 1 block/CU): FFN1, FFN2 z=4.
#define BARR asm volatile("s_barrier" ::: "memory")

template <int EPI>
__global__ __launch_bounds__(512, 2)
void gemm8(const u16* __restrict__ A, const u16* __restrict__ Bt,
           const float* __restrict__ bias, void* __restrict__ Cv,
           int M, int N, int K, int ldA, int ldB) {
    __shared__ u16 sh2[65536];  // 128 KB
    const int tid = threadIdx.x;
    const int lane = tid & 63, w = tid >> 6;
    const int wm = w >> 2, wn = w & 3;
    const int c = lane & 15, g = lane >> 4;
    const int cbase = c * 128 + g * 16;
    const int xo = (c & 7) << 4;

    int nMt = gridDim.x;
    int nwg = gridDim.x * gridDim.y;
    int id = blockIdx.x + nMt * blockIdx.y;
    int qq = nwg >> 3;
    int sid = (id & 7) * qq + (id >> 3);
    int m0 = (sid % nMt) * 256, n0 = (sid / nMt) * 256;
    size_t koff = (size_t)blockIdx.z * K;

    const int nT = K >> 6, nI = nT >> 1;

    const int sr = tid >> 3;
    const int sk = ((tid & 7) * 8) ^ (((tid >> 3) & 7) << 3);
    const u16* gA0 = A + (size_t)(m0 + sr) * ldA + koff + sk;
    const u16* gB0 = Bt + (size_t)(n0 + sr) * ldB + koff + sk;
    const int dst0 = w * 512;  // u16; HW adds lane*16B

#define STG_A(t_, h_) do { \
    const u16* s_ = gA0 + (size_t)(h_) * 128 * ldA + (t_) * 64; \
    u16* l_ = &sh2[((((t_) & 1) * 2 + (h_)) * 8192) + dst0]; \
    gl_lds16(s_, l_); \
    gl_lds16(s_ + (size_t)64 * ldA, l_ + 4096); \
} while (0)
#define STG_B(t_, h_) do { \
    const u16* s_ = gB0 + (size_t)(h_) * 128 * ldB + (t_) * 64; \
    u16* l_ = &sh2[32768 + ((((t_) & 1) * 2 + (h_)) * 8192) + dst0]; \
    gl_lds16(s_, l_); \
    gl_lds16(s_ + (size_t)64 * ldB, l_ + 4096); \
} while (0)

    short8 fa[8], fb0[4], fb1[4];
    floatx4 acc[2][2][4][2];
#pragma unroll
    for (int i = 0; i < 2; i++)
#pragma unroll
        for (int j = 0; j < 2; j++)
#pragma unroll
            for (int a = 0; a < 4; a++)
#pragma unroll
                for (int b2 = 0; b2 < 2; b2++)
                    acc[i][j][a][b2] = (floatx4){0.f, 0.f, 0.f, 0.f};

#define DS_A(d_, qr_) do { \
    int rb_ = ((d_) * 2 + wm) * 16384; \
    _Pragma("unroll") for (int a_ = 0; a_ < 4; a_++) \
    _Pragma("unroll") for (int k_ = 0; k_ < 2; k_++) { \
        int lin_ = (qr_) * 8192 + a_ * 2048 + cbase + k_ * 64; \
        fa[a_ * 2 + k_] = *(const short8*)((const char*)sh2 + rb_ + (lin_ ^ xo)); } \
} while (0)
#define DS_B(d_, qc_, fb_) do { \
    int rb_ = 65536 + ((d_) * 2 + (wn >> 1)) * 16384; \
    _Pragma("unroll") for (int b_ = 0; b_ < 2; b_++) \
    _Pragma("unroll") for (int k_ = 0; k_ < 2; k_++) { \
        int lin_ = (wn & 1) * 8192 + (qc_) * 4096 + b_ * 2048 + cbase + k_ * 64; \
        fb_[b_ * 2 + k_] = *(const short8*)((const char*)sh2 + rb_ + (lin_ ^ xo)); } \
} while (0)
#define MFMA16(qr_, qc_, fb_) do { \
    __builtin_amdgcn_s_setprio(1); \
    _Pragma("unroll") for (int a_ = 0; a_ < 4; a_++) \
    _Pragma("unroll") for (int b_ = 0; b_ < 2; b_++) \
    _Pragma("unroll") for (int k_ = 0; k_ < 2; k_++) \
        acc[qr_][qc_][a_][b_] = __builtin_amdgcn_mfma_f32_16x16x32_bf16( \
            fa[a_ * 2 + k_], fb_[b_ * 2 + k_], acc[qr_][qc_][a_][b_], 0, 0, 0); \
    __builtin_amdgcn_s_setprio(0); \
} while (0)

    // prologue: tile0 full, tile1 A-halves; wait tile0 done (tile1.A in flight)
    STG_B(0, 0); STG_B(0, 1); STG_A(0, 0); STG_A(0, 1);
    STG_A(1, 0); STG_A(1, 1);
    asm volatile("s_waitcnt vmcnt(4)" ::: "memory");
    BARR;

    for (int it2 = 0; it2 < nI; it2++) {
        const int t1 = 2 * it2 + 1, tn0 = t1 + 1, tn1 = t1 + 2;
        // P1 (buf0, qr0,qc0)
        DS_A(0, 0); DS_B(0, 0, fb0);
        STG_B(t1, 0);
        MFMA16(0, 0, fb0); BARR;
        // P2 (qr0,qc1)
        DS_B(0, 1, fb1);
        STG_B(t1, 1);
        MFMA16(0, 1, fb1); BARR;
        // P3 (qr1,qc1)
        DS_A(0, 1);
        if (tn0 < nT) STG_B(tn0, 0);
        MFMA16(1, 1, fb1); BARR;
        // P4 (qr1,qc0)  -- checkpoint: t1 fully resident before P5
        if (tn0 < nT) {
            STG_B(tn0, 1);
            asm volatile("s_waitcnt vmcnt(4)" ::: "memory");
        } else {
            asm volatile("s_waitcnt vmcnt(0)" ::: "memory");
        }
        MFMA16(1, 0, fb0); BARR;
        // P5 (buf1, qr0,qc0)
        DS_A(1, 0); DS_B(1, 0, fb0);
        if (tn0 < nT) STG_A(tn0, 0);
        MFMA16(0, 0, fb0); BARR;
        // P6 (qr0,qc1)
        DS_B(1, 1, fb1);
        if (tn0 < nT) STG_A(tn0, 1);
        MFMA16(0, 1, fb1); BARR;
        // P7 (qr1,qc1)
        DS_A(1, 1);
        if (tn1 < nT) STG_A(tn1, 0);
        MFMA16(1, 1, fb1); BARR;
        // P8 (qr1,qc0) -- checkpoint: tn0 resident before next-iter P1
        if (tn1 < nT) STG_A(tn1, 1);
        if (it2 + 1 < nI) asm volatile("s_waitcnt vmcnt(4)" ::: "memory");
        MFMA16(1, 0, fb0); BARR;
    }

    // epilogue
#pragma unroll
    for (int qr = 0; qr < 2; qr++)
#pragma unroll
        for (int qc = 0; qc < 2; qc++)
#pragma unroll
            for (int a = 0; a < 4; a++)
#pragma unroll
                for (int b2 = 0; b2 < 2; b2++) {
                    int mrow = m0 + wm * 128 + qr * 64 + a * 16 + g * 4;
                    int ncol = n0 + wn * 64 + qc * 32 + b2 * 16 + c;
                    float bv = (EPI == 3) ? 0.f : bias[ncol];
#pragma unroll
                    for (int r = 0; r < 4; r++) {
                        int m = mrow + r;
                        float vvv = acc[qr][qc][a][b2][r] + bv;
                        if (EPI == 0) {
                            int which = ncol >> 10, col = ncol & 1023;
                            if (which == 0) vvv *= 0.125f;
                            int bb = m >> 11, ss = m & 2047, hh = col >> 6, dk = col & 63;
                            ((u16*)Cv)[(size_t)which * ((size_t)B_ * S_ * D_) +
                                       ((((size_t)bb * H_ + hh) * S_) + ss) * DK_ + dk] = f2b(vvv);
                        } else if (EPI == 2) {
                            float u = 0.79788456080286536f * fmaf(0.044715f * vvv, vvv * vvv, vvv);
                            float th = 1.f - 2.f / (1.f + __expf(2.f * u));
                            ((u16*)Cv)[(size_t)m * N + ncol] = f2b(0.5f * vvv * (1.f + th));
                        } else {
                            ((u16*)Cv)[(size_t)blockIdx.z * M * N + (size_t)m * N + ncol] = f2b(vvv);
                        }
                    }
                }
#undef STG_A
#undef STG_B
#undef DS_A
#undef DS_B
#undef MFMA16
}

// ---------------- FFN2 split-K merge: out = x1 + bf2 + sum_z P[z] ----------------
template <int NP>
__global__ __launch_bounds__(256)
void ffn2_merge(const u16* __restrict__ P, const float* __restrict__ x1,
                const float* __restrict__ bf2, float* __restrict__ out) {
    const size_t MN = (size_t)B_ * S_ * D_;
    int e = (blockIdx.x * 256 + threadIdx.x) * 4;
    float4 xv = *(const float4*)&x1[e];
    float4 bv = *(const float4*)&bf2[e & 1023];
    float o0 = xv.x + bv.x, o1 = xv.y + bv.y, o2 = xv.z + bv.z, o3 = xv.w + bv.w;
#pragma unroll
    for (int z = 0; z < NP; z++) {
        ushort4_t pv = *(const ushort4_t*)&P[z * MN + e];
        o0 += b2f(pv[0]); o1 += b2f(pv[1]); o2 += b2f(pv[2]); o3 += b2f(pv[3]);
    }
    *(float4*)&out[e] = (float4){o0, o1, o2, o3};
}

// ---------------- MFMA sparse strided attention, 38 KB LDS union -----------------
#define MAXB_ 14
__global__ __launch_bounds__(256)
void attn4(const u16* __restrict__ q, const u16* __restrict__ k,
           const u16* __restrict__ v, const int* __restrict__ mask,
           const int* __restrict__ tileOK, u16* __restrict__ ob) {
    __shared__ u16 sh[19456];            // 38,912 B
    u16* Kw = sh;                        // [192*72]; P[64*200] overlays later
    u16* Qs = sh + 13824;                // [64*72]
    u16* Vh = sh + 12800;                // [64*104] V^T half (built after scores)

    const int bh = blockIdx.x;
    const int i0 = (31 - blockIdx.y) * 64;
    const int b  = bh >> 4, h = bh & 15;
    const int t  = threadIdx.x;
    const int lane = t & 63, w = t >> 6;
    const int c = lane & 15, g = lane >> 4;
    const int g4 = g * 4;
    const int qloc16 = w * 16;

    const u16* qg = q + ((size_t)bh * S_ + i0) * DK_;
    const u16* kg = k + (size_t)bh * S_ * DK_;
    const u16* vg = v + (size_t)bh * S_ * DK_;

    const int wlo = (i0 >= 128) ? i0 - 128 : 0;
    const int wn  = i0 + 64 - wlo;             // 64 / 128 / 192
    const int nb  = (i0 >= 256) ? (i0 >> 7) - 1 : 0;
    const int jb0 = i0 & 127;
    const int dd0 = i0 - wlo;

    bool allOK = true;
    {
        const int* rowf = tileOK + (i0 >> 7) * 16;
        int jt0 = wlo >> 7, jt1 = (i0 + 63) >> 7;
        for (int jt = jt0; jt <= jt1; jt++) allOK &= (rowf[jt] != 0);
        for (int m = 0; m < nb; m++) allOK &= (rowf[m] != 0);
    }

    // ---- P0: stage Qs + Kw
    for (int e = t; e < 64 * 8; e += 256) {
        int row = e >> 3, dc = e & 7;
        *(short8*)&Qs[row * 72 + dc * 8] = *(const short8*)(qg + row * 64 + dc * 8);
    }
    for (int e = t; e < wn * 8; e += 256) {
        int row = e >> 3, dc = e & 7;
        *(short8*)&Kw[row * 72 + dc * 8] = *(const short8*)(kg + (size_t)(wlo + row) * 64 + dc * 8);
    }
    __syncthreads();

    // ---- P1: band scores -> sbr[m]
    float sbr[MAXB_];
    {
        short8 qv0 = *(const short8*)&Qs[(qloc16 + c) * 72 + g * 8];
        short8 qv1 = *(const short8*)&Qs[(qloc16 + c) * 72 + 32 + g * 8];
#pragma unroll
        for (int m = 0; m < MAXB_; m++) {
            sbr[m] = NEG_;
            if (m < nb) {
                int jrow = jb0 + (m << 7) + qloc16 + c;
                short8 kv0 = *(const short8*)(kg + (size_t)jrow * 64 + g * 8);
                short8 kv1 = *(const short8*)(kg + (size_t)jrow * 64 + 32 + g * 8);
                float p = 0.f;
#pragma unroll
                for (int i = 0; i < 8; i++) {
                    p += b2f((u16)qv0[i]) * b2f((u16)kv0[i]);
                    p += b2f((u16)qv1[i]) * b2f((u16)kv1[i]);
                }
                p += __shfl_xor(p, 16);
                p += __shfl_xor(p, 32);
                if (!allOK && mask[(size_t)(i0 + qloc16 + c) * S_ + jrow] == 0) p = NEG_;
                sbr[m] = p;
            }
        }
    }

    // ---- P2: window scores via MFMA
    floatx4 sc[12];
#pragma unroll
    for (int ct = 0; ct < 12; ct++) sc[ct] = (floatx4){0.f, 0.f, 0.f, 0.f};
    {
        short8 fa0 = *(const short8*)&Qs[(qloc16 + c) * 72 + g * 8];
        short8 fa1 = *(const short8*)&Qs[(qloc16 + c) * 72 + 32 + g * 8];
#pragma unroll
        for (int ct = 0; ct < 12; ct++) {
            short8 fb0 = *(const short8*)&Kw[(ct * 16 + c) * 72 + g * 8];
            short8 fb1 = *(const short8*)&Kw[(ct * 16 + c) * 72 + 32 + g * 8];
            sc[ct] = __builtin_amdgcn_mfma_f32_16x16x32_bf16(fa0, fb0, sc[ct], 0, 0, 0);
            sc[ct] = __builtin_amdgcn_mfma_f32_16x16x32_bf16(fa1, fb1, sc[ct], 0, 0, 0);
        }
    }

    // ---- P3: causal/range mask (+fallback user mask) + softmax stats
#pragma unroll
    for (int ct = 0; ct < 12; ct++) {
        int cidx = ct * 16 + c;
        int j = wlo + cidx;
#pragma unroll
        for (int r = 0; r < 4; r++) {
            int qloc = qloc16 + g4 + r;
            int d = dd0 + qloc - cidx;
            bool ok = (d >= 0) && (d <= 128);
            if (ok && !allOK) ok = (mask[(size_t)(i0 + qloc) * S_ + j] != 0);
            sc[ct][r] = ok ? sc[ct][r] : NEG_;
        }
    }

    float mv[4], inv[4];
#pragma unroll
    for (int r = 0; r < 4; r++) {
        float bs[MAXB_];
#pragma unroll
        for (int m = 0; m < MAXB_; m++)
            bs[m] = (m < nb) ? __shfl(sbr[m], g4 + r, 64) : NEG_;
        float mm = -1e30f;
#pragma unroll
        for (int ct = 0; ct < 12; ct++) mm = fmaxf(mm, sc[ct][r]);
        mm = fmaxf(mm, __shfl_xor(mm, 1));
        mm = fmaxf(mm, __shfl_xor(mm, 2));
        mm = fmaxf(mm, __shfl_xor(mm, 4));
        mm = fmaxf(mm, __shfl_xor(mm, 8));
#pragma unroll
        for (int m = 0; m < MAXB_; m++)
            if (m < nb) mm = fmaxf(mm, bs[m]);
        float sum = 0.f;
#pragma unroll
        for (int ct = 0; ct < 12; ct++) {
            float e = __expf(sc[ct][r] - mm);
            sc[ct][r] = e;
            sum += e;
        }
        sum += __shfl_xor(sum, 1);
        sum += __shfl_xor(sum, 2);
        sum += __shfl_xor(sum, 4);
        sum += __shfl_xor(sum, 8);
#pragma unroll
        for (int m = 0; m < MAXB_; m++)
            if (m < nb) sum += __expf(bs[m] - mm);
        mv[r] = mm;
        inv[r] = 1.f / sum;
    }

    // ---- P4: write P over Kw; build Vh half0 (j 0..95)
    __syncthreads();
    u16* P = Kw;
#pragma unroll
    for (int ct = 0; ct < 12; ct++)
#pragma unroll
        for (int r = 0; r < 4; r++)
            P[(qloc16 + g4 + r) * 200 + ct * 16 + c] = f2b(sc[ct][r]);

    for (int e = t; e < 768; e += 256) {
        int dc = e / 96, jl = e - dc * 96;
        short8 val = {0, 0, 0, 0, 0, 0, 0, 0};
        if (jl < wn) val = *(const short8*)(vg + (size_t)(wlo + jl) * 64 + dc * 8);
#pragma unroll
        for (int i = 0; i < 8; i++) Vh[(dc * 8 + i) * 104 + jl] = (u16)val[i];
    }
    __syncthreads();

    // ---- P5a: window PV half0 via MFMA
    floatx4 o[4];
#pragma unroll
    for (int nt = 0; nt < 4; nt++) o[nt] = (floatx4){0.f, 0.f, 0.f, 0.f};
#pragma unroll
    for (int ks = 0; ks < 3; ks++) {
        short8 pa = *(const short8*)&P[(qloc16 + c) * 200 + ks * 32 + g * 8];
#pragma unroll
        for (int nt = 0; nt < 4; nt++) {
            short8 vb = *(const short8*)&Vh[(nt * 16 + c) * 104 + ks * 32 + g * 8];
            o[nt] = __builtin_amdgcn_mfma_f32_16x16x32_bf16(pa, vb, o[nt], 0, 0, 0);
        }
    }

    // ---- P5b: rebuild Vh for half1 (j 96..191) and finish PV (uniform branch)
    if (wn > 96) {
        __syncthreads();
        for (int e = t; e < 768; e += 256) {
            int dc = e / 96, jl = e - dc * 96;
            int j2 = 96 + jl;
            short8 val = {0, 0, 0, 0, 0, 0, 0, 0};
            if (j2 < wn) val = *(const short8*)(vg + (size_t)(wlo + j2) * 64 + dc * 8);
#pragma unroll
            for (int i = 0; i < 8; i++) Vh[(dc * 8 + i) * 104 + jl] = (u16)val[i];
        }
        __syncthreads();
#pragma unroll
        for (int ks = 0; ks < 3; ks++) {
            short8 pa = *(const short8*)&P[(qloc16 + c) * 200 + 96 + ks * 32 + g * 8];
#pragma unroll
            for (int nt = 0; nt < 4; nt++) {
                short8 vb = *(const short8*)&Vh[(nt * 16 + c) * 104 + ks * 32 + g * 8];
                o[nt] = __builtin_amdgcn_mfma_f32_16x16x32_bf16(pa, vb, o[nt], 0, 0, 0);
            }
        }
    }

    // ---- P6: band PV via per-lane register loads
#pragma unroll
    for (int m = 0; m < MAXB_; m++) {
        if (m < nb) {
            int vbase = jb0 + (m << 7) + qloc16 + g4;
            u16 vv[4][4];
#pragma unroll
            for (int r = 0; r < 4; r++)
#pragma unroll
                for (int nt = 0; nt < 4; nt++)
                    vv[r][nt] = vg[(size_t)(vbase + r) * 64 + nt * 16 + c];
#pragma unroll
            for (int r = 0; r < 4; r++) {
                float bs = __shfl(sbr[m], g4 + r, 64);
                float pb = __expf(bs - mv[r]);
#pragma unroll
                for (int nt = 0; nt < 4; nt++)
                    o[nt][r] += pb * b2f(vv[r][nt]);
            }
        }
    }

    // ---- P7: normalize + write [B,S,D] bf16
#pragma unroll
    for (int nt = 0; nt < 4; nt++) {
#pragma unroll
        for (int r = 0; r < 4; r++) {
            int qi = i0 + qloc16 + g4 + r;
            ob[((size_t)b * S_ + qi) * D_ + h * 64 + nt * 16 + c] = f2b(o[nt][r] * inv[r]);
        }
    }
}

extern "C" void kernel_launch(void* const* d_in, const int* in_sizes, int n_in,
                              void* d_out, int out_size, void* d_ws, size_t ws_size,
                              hipStream_t stream) {
    const float* x    = (const float*)d_in[0];
    const int*   mask = (const int*)  d_in[1];
    const float* Wq   = (const float*)d_in[2];
    const float* bq   = (const float*)d_in[3];
    const float* Wk   = (const float*)d_in[4];
    const float* bk   = (const float*)d_in[5];
    const float* Wv   = (const float*)d_in[6];
    const float* bv   = (const float*)d_in[7];
    const float* Wo   = (const float*)d_in[8];
    const float* bo   = (const float*)d_in[9];
    const float* W1   = (const float*)d_in[10];
    const float* bf1  = (const float*)d_in[11];
    const float* W2   = (const float*)d_in[12];
    const float* bf2  = (const float*)d_in[13];
    const float* g1   = (const float*)d_in[14];
    const float* bl1  = (const float*)d_in[15];
    const float* g2   = (const float*)d_in[16];
    const float* bl2  = (const float*)d_in[17];

    char* wsb = (char*)d_ws;
    const size_t MB = 1024 * 1024;
    u16*   WtQKV  = (u16*)(wsb + 0);          // 6 MB; WtO contiguous after
    u16*   WtO    = (u16*)(wsb + 6 * MB);     // 2 MB
    u16*   Wt1    = (u16*)(wsb + 8 * MB);     // 8 MB
    u16*   Wt2    = (u16*)(wsb + 16 * MB);    // 8 MB
    u16*   n1b    = (u16*)(wsb + 24 * MB);    // 8 MB (reused as n2b)
    u16*   qkv    = (u16*)(wsb + 32 * MB);    // 24 MB (dead after attn)
    u16*   obb    = (u16*)(wsb + 56 * MB);    // 8 MB (dead after Wo gemm)
    float* x1     = (float*)(wsb + 32 * MB);  // 16 MB over dead q|k (live thru merge)
    u16*   ff1b   = (u16*)(wsb + 48 * MB);    // 33.5 MB over dead v|obb
    u16*   Ppart  = (u16*)(wsb + 82 * MB);    // 32 MB: FFN2 4x bf16 partials
    u16*   PpartO = (u16*)(wsb + 82 * MB);    // 16 MB: Wo 2x partials (dead before FFN2)
    float* bcat   = (float*)(wsb + 114 * MB); // 12 KB
    int*   tflag  = (int*)(wsb + 115 * MB);   // 1 KB
    u16*   n2b    = n1b;

    const int M = B_ * S_;  // 4096
    const size_t SZ = (size_t)B_ * S_ * D_;

    // 0. mask tile flags, weight transpose + convert, bias concat
    mask_tiles<<<dim3(16, 16), 256, 0, stream>>>(mask, tflag);
    tconv4<<<dim3(32, 32, 4), 256, 0, stream>>>(Wq, Wk, Wv, Wo, WtQKV);
    tconv<<<dim3(128, 32), 256, 0, stream>>>(W1, Wt1, 1024, 4096);
    tconv<<<dim3(32, 128), 256, 0, stream>>>(W2, Wt2, 4096, 1024);
    catbias<<<12, 256, 0, stream>>>(bq, bk, bv, bcat);

    // 1. LN1 -> bf16
    ln_bf16<<<M, 256, 0, stream>>>(x, g1, bl1, n1b);

    // 2. fused QKV projection (N=3072) -> bf16 [B,H,S,DK] x3 (Q pre-scaled 1/8)
    //    128^2 tile -> 768 blocks (3/CU): fills all CUs (gemm8 grid 192 left 25% idle)
    gemm_bt<0><<<dim3(32, 24), 256, 0, stream>>>(n1b, WtQKV, bcat, nullptr, qkv,
                                                 M, 3072, 1024, 1024, 1024);

    // 3. sparse strided attention (MFMA) -> bf16 [B,S,D]
    attn4<<<dim3(32, 32), 256, 0, stream>>>(qkv, qkv + SZ, qkv + 2 * SZ, mask, tflag, obb);

    // 4. Wo split-K=2 partials (512 blocks, 2/CU), then fused merge(+x+bo) + LN2
    gemm_bt<3><<<dim3(32, 8, 2), 256, 0, stream>>>(obb, WtO, nullptr, nullptr, PpartO,
                                                   M, 1024, 512, 1024, 1024);
    merge_ln<<<M, 256, 0, stream>>>(PpartO, x, bo, g2, bl2, x1, n2b);

    // 6. ff1 = GELU(n2 @ W1 + bf1) -> bf16  (256 blocks == 256 CUs: gemm8)
    gemm8<2><<<dim3(16, 16, 1), 512, 0, stream>>>(n2b, Wt1, bf1, ff1b,
                                                  M, 4096, 1024, 1024, 1024);

    // 7. FFN2 split-K=4 on gemm8 (16x4x4 = 256 blocks == 256 CUs): partials -> merge
    gemm8<3><<<dim3(16, 4, 4), 512, 0, stream>>>(ff1b, Wt2, nullptr, Ppart,
                                                 M, 1024, 1024, 4096, 4096);
    ffn2_merge<4><<<(int)(SZ / 1024), 256, 0, stream>>>(Ppart, x1, bf2, (float*)d_out);
}